// Round 17
// baseline (552.603 us; speedup 1.0000x reference)
//
#include <hip/hip_runtime.h>
#include <math.h>

#define HDIM 64
#define NHEAD 12
#define HDN 768
#define QKVN 2304
#define FFDIM 3072
#define LPAST 50
#define SEQ 512
#define NBATCH 16
#define TKV (LPAST + SEQ)     // 562
#define TKVP 576
#define MTOK (NBATCH * SEQ)   // 8192
#define NBH (NBATCH * NHEAD)  // 192

typedef __attribute__((ext_vector_type(8))) short short8;
typedef __attribute__((ext_vector_type(4))) float f32x4;

__device__ __forceinline__ ushort f2bf(float x) {
    union { float f; unsigned u; } c; c.f = x;
    unsigned r = (c.u + 0x7fffu + ((c.u >> 16) & 1u)) >> 16;
    return (ushort)r;
}
__device__ __forceinline__ float bf2f(ushort u) { return __uint_as_float((unsigned)u << 16); }
__device__ __forceinline__ float gelu_fast(float v) {
    float u = 0.7978845608f * v * fmaf(0.044715f * v, v, 1.0f);
    float e = __expf(2.0f * u);
    float th = 1.0f - 2.0f / (e + 1.0f);
    return 0.5f * v * (1.0f + th);
}

#define GLOAD_LDS16(gsrc, ldst)                                                    \
    __builtin_amdgcn_global_load_lds(                                              \
        (const __attribute__((address_space(1))) void*)(gsrc),                     \
        (__attribute__((address_space(3))) void*)(ldst), 16, 0, 0)

// ---------------------------------------------------------------------------
// prep: fused prologue (cast hs, pack qkv bias, all weight transposes)
// ---------------------------------------------------------------------------
__global__ __launch_bounds__(256) void prep(
    const float* __restrict__ hs, ushort* __restrict__ hs_bf,
    const float* __restrict__ bq, const float* __restrict__ bk,
    const float* __restrict__ bv, float* __restrict__ bqkv,
    const float* __restrict__ Wq, const float* __restrict__ Wk,
    const float* __restrict__ Wv, const float* __restrict__ Wo,
    ushort* __restrict__ WqT, ushort* __restrict__ WkT,
    ushort* __restrict__ WvT, ushort* __restrict__ WoT,
    const float* __restrict__ Wi, ushort* __restrict__ WiT,
    const float* __restrict__ Wf, ushort* __restrict__ WfT)
{
    __shared__ float tls[32][33];
    int bid = blockIdx.x;
    const int tid = threadIdx.x;

    if (bid < 6144) {
        int i = bid * 256 + tid;
        float4 v = ((const float4*)hs)[i];
        ushort4 o; o.x = f2bf(v.x); o.y = f2bf(v.y); o.z = f2bf(v.z); o.w = f2bf(v.w);
        ((ushort4*)hs_bf)[i] = o;
        return;
    }
    bid -= 6144;
    if (bid < 9) {
        int i = bid * 256 + tid;
        bqkv[i] = i < HDN ? bq[i] : (i < 2 * HDN ? bk[i - HDN] : bv[i - 2 * HDN]);
        return;
    }
    bid -= 9;

    const float* W; ushort* WT; int K, N, bx, by;
    if (bid < 2304) {
        int z = bid / 576, r = bid % 576;
        W = z == 0 ? Wq : z == 1 ? Wk : z == 2 ? Wv : Wo;
        WT = z == 0 ? WqT : z == 1 ? WkT : z == 2 ? WvT : WoT;
        K = HDN; N = HDN; bx = r % 24; by = r / 24;
    } else if (bid < 4608) {
        int r = bid - 2304; W = Wi; WT = WiT; K = HDN; N = FFDIM; bx = r % 96; by = r / 96;
    } else {
        int r = bid - 4608; W = Wf; WT = WfT; K = FFDIM; N = HDN; bx = r % 24; by = r / 24;
    }
    const int n0 = bx * 32, k0 = by * 32;
    const int tx = tid & 31, ty = tid >> 5;
    #pragma unroll
    for (int i = 0; i < 4; ++i)
        tls[ty + i * 8][tx] = W[(size_t)(k0 + ty + i * 8) * N + n0 + tx];
    __syncthreads();
    #pragma unroll
    for (int i = 0; i < 4; ++i)
        WT[(size_t)(n0 + ty + i * 8) * K + k0 + tx] = f2bf(tls[tx][ty + i * 8]);
}

// ---------------------------------------------------------------------------
// gemm_t: 128xBN-tile bf16 MFMA GEMM (NT), BK=32, 2-buffer LDS --
// HIGH OCCUPANCY variant: 32KB LDS (BN=128) -> 5 blk/CU = 20 waves/CU;
// 24KB (BN=64) -> 6 blk/CU. TLP fills the per-step sync bubbles (m114
// wave-overlap mechanism). Operand-swapped MFMA (C frag: row=lane&15,
// col=(lane>>4)*4+rr -> packed ushort4 stores). st_16x32 XOR swizzle with
// inverse-swizzled global source. Split-K via blockIdx.z.
// EPI: 0=+bias ; 1=+bias+resid(f32) ; 2=FAST-gelu(+bias) ;
//      4=+bias+resid(bf16) ; 5=raw partial. All outputs bf16.
// ---------------------------------------------------------------------------
template<int EPI, int BN>
__global__ __launch_bounds__(256, BN == 64 ? 6 : 5) void gemm_t(
    const ushort* __restrict__ A, const ushort* __restrict__ B,
    int lda, int ldb,
    const float* __restrict__ bias, const float* __restrict__ resid,
    const ushort* __restrict__ resid_bf,
    ushort* __restrict__ Cout, int M, int N, int K)
{
    constexpr int NF = BN / 32;              // B frags per wave (4 or 2)
    constexpr int NBG = BN / 64;             // B gloads per thread (2 or 1)
    constexpr int BUFU = 4096 + BN * 32;     // ushorts per buffer
    __shared__ ushort sm[2 * BUFU];

    const int tid = threadIdx.x;
    const int lane = tid & 63;
    const int wv = tid >> 6;
    const int wr = wv >> 1, wc = wv & 1;
    const int bm = blockIdx.x * 128, bn = blockIdx.y * BN;
    const int lr = lane & 15, lg = lane >> 4;
    const int swzu = ((lr * 64 + lg * 16) ^ ((lr & 8) << 2)) >> 1;
    const size_t kzoff = (size_t)blockIdx.z * K;

    // staging decode: linear LDS slot -> swizzled logical (row, k) source
    int arow[2], akk[2], brow[NBG], bkk[NBG];
    #pragma unroll
    for (int r = 0; r < 2; ++r) {
        int o = (tid + 256 * r) * 16;
        int st = o >> 10, q = o & 1023;
        q ^= ((q >> 9) & 1) << 5;
        arow[r] = st * 16 + (q >> 6);
        akk[r] = (q & 63) >> 1;
    }
    #pragma unroll
    for (int r = 0; r < NBG; ++r) {
        int o = (tid + 256 * r) * 16;
        int st = o >> 10, q = o & 1023;
        q ^= ((q >> 9) & 1) << 5;
        brow[r] = st * 16 + (q >> 6);
        bkk[r] = (q & 63) >> 1;
    }
    const ushort* Abase = A + (size_t)bm * lda + kzoff;
    const ushort* Bbase = B + (size_t)bn * ldb + kzoff;
    const int nt = K >> 5;

    f32x4 acc[4][NF] = {};

#define STAGE(T, BUF)                                                            \
    do {                                                                         \
        const int k0_ = (T) << 5;                                                \
        char* base_ = (char*)(sm + (BUF) * BUFU);                                \
        _Pragma("unroll")                                                        \
        for (int r_ = 0; r_ < 2; ++r_)                                           \
            GLOAD_LDS16(Abase + (size_t)arow[r_] * lda + k0_ + akk[r_],          \
                        base_ + (tid + 256 * r_) * 16);                          \
        _Pragma("unroll")                                                        \
        for (int r_ = 0; r_ < NBG; ++r_)                                         \
            GLOAD_LDS16(Bbase + (size_t)brow[r_] * ldb + k0_ + bkk[r_],          \
                        base_ + 8192 + (tid + 256 * r_) * 16);                   \
    } while (0)

    STAGE(0, 0);
    asm volatile("s_waitcnt vmcnt(0)" ::: "memory");
    __builtin_amdgcn_sched_barrier(0);
    __builtin_amdgcn_s_barrier();
    __builtin_amdgcn_sched_barrier(0);

    int buf = 0;
    for (int t = 0; t < nt; ++t) {
        if (t + 1 < nt) STAGE(t + 1, buf ^ 1);
        const ushort* ab = sm + buf * BUFU;
        short8 af[4], bfv[NF];
        #pragma unroll
        for (int i = 0; i < 4; ++i)
            af[i] = *(const short8*)(ab + (wr * 4 + i) * 512 + swzu);
        #pragma unroll
        for (int j = 0; j < NF; ++j)
            bfv[j] = *(const short8*)(ab + 4096 + (wc * NF + j) * 512 + swzu);
        __builtin_amdgcn_s_setprio(1);
        #pragma unroll
        for (int i = 0; i < 4; ++i)
            #pragma unroll
            for (int j = 0; j < NF; ++j)
                acc[i][j] = __builtin_amdgcn_mfma_f32_16x16x32_bf16(
                    bfv[j], af[i], acc[i][j], 0, 0, 0);
        __builtin_amdgcn_s_setprio(0);
        asm volatile("s_waitcnt vmcnt(0)" ::: "memory");
        __builtin_amdgcn_sched_barrier(0);
        __builtin_amdgcn_s_barrier();
        __builtin_amdgcn_sched_barrier(0);
        buf ^= 1;
    }
#undef STAGE

    // epilogue: row = ...+lr (fixed per lane), col quad = ...+lg*4 (+rr)
    ushort* Cz = Cout + (size_t)blockIdx.z * M * N;
    #pragma unroll
    for (int i = 0; i < 4; ++i) {
        const int row = bm + wr * 64 + i * 16 + lr;
        #pragma unroll
        for (int j = 0; j < NF; ++j) {
            const int col = bn + wc * (BN / 2) + j * 16 + lg * 4;
            const size_t idx = (size_t)row * N + col;
            float v0 = acc[i][j][0], v1 = acc[i][j][1],
                  v2 = acc[i][j][2], v3 = acc[i][j][3];
            if (EPI != 5) {
                float4 b4 = *(const float4*)&bias[col];
                v0 += b4.x; v1 += b4.y; v2 += b4.z; v3 += b4.w;
            }
            if (EPI == 1) {
                float4 r4 = *(const float4*)&resid[idx];
                v0 += r4.x; v1 += r4.y; v2 += r4.z; v3 += r4.w;
            }
            if (EPI == 4) {
                ushort4 rb = *(const ushort4*)&resid_bf[idx];
                v0 += bf2f(rb.x); v1 += bf2f(rb.y);
                v2 += bf2f(rb.z); v3 += bf2f(rb.w);
            }
            if (EPI == 2) {
                v0 = gelu_fast(v0); v1 = gelu_fast(v1);
                v2 = gelu_fast(v2); v3 = gelu_fast(v3);
            }
            ushort4 o;
            o.x = f2bf(v0); o.y = f2bf(v1); o.z = f2bf(v2); o.w = f2bf(v3);
            *(ushort4*)&Cz[idx] = o;
        }
    }
}

// ---------------------------------------------------------------------------
// kvAll: fused K cache + transposed V cache (bug-faithful past_key prefix).
// ---------------------------------------------------------------------------
__global__ __launch_bounds__(256) void kvAll(
    const ushort* __restrict__ qkv, const float* __restrict__ past_key,
    ushort* __restrict__ kf, ushort* __restrict__ vt)
{
    __shared__ ushort td[64][72];
    const int bh = blockIdx.x / 9;
    const int t0 = (blockIdx.x % 9) * 64;
    const int b = bh / NHEAD, h = bh % NHEAD;
    const int trow = threadIdx.x >> 2, seg = threadIdx.x & 3;
    const int t = t0 + trow;

    ushort kv16[16], vv16[16];
    if (t < LPAST) {
        const float* pk = past_key + ((size_t)bh * LPAST + t) * HDIM + seg * 16;
        #pragma unroll
        for (int i = 0; i < 4; ++i) {
            float4 f = ((const float4*)pk)[i];
            kv16[i * 4 + 0] = f2bf(f.x); kv16[i * 4 + 1] = f2bf(f.y);
            kv16[i * 4 + 2] = f2bf(f.z); kv16[i * 4 + 3] = f2bf(f.w);
        }
        #pragma unroll
        for (int i = 0; i < 16; ++i) vv16[i] = kv16[i];
    } else if (t < TKV) {
        const ushort* kp = qkv + ((size_t)(b * SEQ + (t - LPAST))) * QKVN
                               + HDN + h * HDIM + seg * 16;
        *(uint4*)&kv16[0] = ((const uint4*)kp)[0];
        *(uint4*)&kv16[8] = ((const uint4*)kp)[1];
        const ushort* vp = kp + HDN;
        *(uint4*)&vv16[0] = ((const uint4*)vp)[0];
        *(uint4*)&vv16[8] = ((const uint4*)vp)[1];
    } else {
        #pragma unroll
        for (int i = 0; i < 16; ++i) { kv16[i] = 0; vv16[i] = 0; }
    }

    if (t < TKV) {
        ushort* kd = kf + (((size_t)bh * TKV + t) << 6) + seg * 16;
        *(uint4*)kd = *(uint4*)&kv16[0];
        *(uint4*)(kd + 8) = *(uint4*)&kv16[8];
    }

    #pragma unroll
    for (int i = 0; i < 16; ++i) td[trow][seg * 16 + i] = vv16[i];
    __syncthreads();

    const int d = threadIdx.x >> 2;
    ushort o[16];
    #pragma unroll
    for (int i = 0; i < 16; ++i) o[i] = td[seg * 16 + i][d];
    ushort* dst = vt + ((size_t)bh * HDIM + d) * TKVP + t0 + seg * 16;
    *(uint4*)dst = *(uint4*)&o[0];
    *(uint4*)(dst + 8) = *(uint4*)&o[8];
}

// ---------------------------------------------------------------------------
// attn4: MFMA flash attention, fixed-max softmax (scores bounded; see R9).
// XCD-grouped blockIdx remap. (Best-measured R14 version, unchanged.)
// ---------------------------------------------------------------------------
__global__ __launch_bounds__(256) void attn4(
    const ushort* __restrict__ qkv, const ushort* __restrict__ kf,
    const ushort* __restrict__ vt, const float* __restrict__ mask,
    ushort* __restrict__ ctx)
{
    __shared__ ushort Ks[64 * 64];
    __shared__ ushort Vs[64 * 64];
    __shared__ ushort Ps[4][16 * 64];

    const int wv = threadIdx.x >> 6, lane = threadIdx.x & 63;
    const int lr = lane & 15, lg = lane >> 4;
    const int bid = blockIdx.x;
    const int xcd = bid & 7, gi = bid >> 3;
    const int bh = xcd * (NBH / 8) + (gi >> 3);
    const int s0 = (gi & 7) * 64;
    const int b = bh / NHEAD, h = bh % NHEAD;

    short8 af[2];
    {
        const ushort* qp = qkv + ((size_t)(b * SEQ + s0 + wv * 16 + lr)) * QKVN
                               + h * HDIM + lg * 8;
        af[0] = *(const short8*)qp;
        af[1] = *(const short8*)(qp + 32);
    }

    const ushort* kbase = kf + (size_t)bh * TKV * HDIM;
    const ushort* vbase = vt + (size_t)bh * HDIM * TKVP;

    float l[4] = {};
    f32x4 ctxa[4] = {};

    for (int kt = 0; kt < 9; ++kt) {
        const int t0 = kt * 64;
        #pragma unroll
        for (int r = 0; r < 2; ++r) {
            int sl = (int)threadIdx.x + 256 * r;
            int row = sl >> 3, p = sl & 7;
            int j = p ^ (row & 7);
            int trow = t0 + row; if (trow > TKV - 1) trow = TKV - 1;
            GLOAD_LDS16(kbase + ((size_t)trow << 6) + j * 8, (char*)Ks + sl * 16);
        }
        #pragma unroll
        for (int r = 0; r < 2; ++r) {
            int sl = (int)threadIdx.x + 256 * r;
            int row = sl >> 3, p = sl & 7;
            int j = p ^ (row & 7);
            GLOAD_LDS16(vbase + (size_t)row * TKVP + t0 + j * 8, (char*)Vs + sl * 16);
        }
        __syncthreads();

        f32x4 sa[4] = {};
        #pragma unroll
        for (int kb = 0; kb < 4; ++kb) {
            const int key = kb * 16 + lr;
            #pragma unroll
            for (int c = 0; c < 2; ++c) {
                const int phys = (c * 4 + lg) ^ (key & 7);
                short8 kfrag = *(const short8*)&Ks[key * 64 + phys * 8];
                sa[kb] = __builtin_amdgcn_mfma_f32_16x16x32_bf16(
                    af[c], kfrag, sa[kb], 0, 0, 0);
            }
        }

        #pragma unroll
        for (int kb = 0; kb < 4; ++kb) {
            const int t = t0 + kb * 16 + lr;
            float addv;
            if (t >= TKV) addv = -1e30f;
            else addv = ((t < LPAST) ? 1.0f : mask[(size_t)b * SEQ + (t - LPAST)]) - 4.0f;
            const int key = kb * 16 + lr;
            #pragma unroll
            for (int r = 0; r < 4; ++r) {
                float p = __expf(fmaf(sa[kb][r], 0.125f, addv));
                l[r] += p;
                const int q_ = lg * 4 + r;
                const int phys = (key >> 3) ^ (q_ & 7);
                Ps[wv][q_ * 64 + phys * 8 + (key & 7)] = f2bf(p);
            }
        }

        short8 pa[2];
        #pragma unroll
        for (int c = 0; c < 2; ++c) {
            const int phys = (c * 4 + lg) ^ (lr & 7);
            pa[c] = *(const short8*)&Ps[wv][lr * 64 + phys * 8];
        }
        #pragma unroll
        for (int dg = 0; dg < 4; ++dg) {
            const int d = dg * 16 + lr;
            #pragma unroll
            for (int c = 0; c < 2; ++c) {
                const int phys = (c * 4 + lg) ^ (d & 7);
                short8 vfrag = *(const short8*)&Vs[d * 64 + phys * 8];
                ctxa[dg] = __builtin_amdgcn_mfma_f32_16x16x32_bf16(
                    pa[c], vfrag, ctxa[dg], 0, 0, 0);
            }
        }
        __syncthreads();
    }

    #pragma unroll
    for (int r = 0; r < 4; ++r) {
        float s = l[r];
        s += __shfl_xor(s, 1); s += __shfl_xor(s, 2);
        s += __shfl_xor(s, 4); s += __shfl_xor(s, 8);
        l[r] = 1.0f / s;
    }
    #pragma unroll
    for (int r = 0; r < 4; ++r) {
        const int q_ = s0 + wv * 16 + lg * 4 + r;
        const size_t base = ((size_t)(b * SEQ + q_)) * HDN + h * HDIM;
        #pragma unroll
        for (int dg = 0; dg < 4; ++dg)
            ctx[base + dg * 16 + lr] = f2bf(ctxa[dg][r] * l[r]);
    }
}

// ---------------------------------------------------------------------------
// LayerNorm(768) over bf16 input; f32 out and/or bf16 out (either null).
// ---------------------------------------------------------------------------
__global__ __launch_bounds__(256) void layernorm3(
    const ushort* __restrict__ x, const float* __restrict__ g,
    const float* __restrict__ b, float* __restrict__ out,
    ushort* __restrict__ out_bf)
{
    const size_t row = blockIdx.x;
    const ushort* xr = &x[row * HDN];
    const int t = threadIdx.x;

    float v0 = bf2f(xr[t]), v1 = bf2f(xr[t + 256]), v2 = bf2f(xr[t + 512]);

    __shared__ float red[4];
    float s = v0 + v1 + v2;
    #pragma unroll
    for (int off = 32; off > 0; off >>= 1) s += __shfl_xor(s, off);
    if ((t & 63) == 0) red[t >> 6] = s;
    __syncthreads();
    float mean = (red[0] + red[1] + red[2] + red[3]) * (1.0f / 768.0f);

    float d0 = v0 - mean, d1 = v1 - mean, d2 = v2 - mean;
    float vs = d0 * d0 + d1 * d1 + d2 * d2;
    #pragma unroll
    for (int off = 32; off > 0; off >>= 1) vs += __shfl_xor(vs, off);
    __syncthreads();
    if ((t & 63) == 0) red[t >> 6] = vs;
    __syncthreads();
    float var = (red[0] + red[1] + red[2] + red[3]) * (1.0f / 768.0f);
    float rstd = rsqrtf(var + 1e-12f);

    float o0 = d0 * rstd * g[t] + b[t];
    float o1 = d1 * rstd * g[t + 256] + b[t + 256];
    float o2 = d2 * rstd * g[t + 512] + b[t + 512];
    if (out) {
        out[row * HDN + t] = o0;
        out[row * HDN + t + 256] = o1;
        out[row * HDN + t + 512] = o2;
    }
    if (out_bf) {
        out_bf[row * HDN + t] = f2bf(o0);
        out_bf[row * HDN + t + 256] = f2bf(o1);
        out_bf[row * HDN + t + 512] = f2bf(o2);
    }
}

// ---------------------------------------------------------------------------
// ln_red: fused split-K reduce (p0+p1+bias+resid) + LayerNorm -> f32 out.
// ---------------------------------------------------------------------------
__global__ __launch_bounds__(256) void ln_red(
    const ushort* __restrict__ p0, const ushort* __restrict__ p1,
    const float* __restrict__ bias, const ushort* __restrict__ resid,
    const float* __restrict__ g, const float* __restrict__ b,
    float* __restrict__ out)
{
    const size_t row = blockIdx.x;
    const size_t base = row * HDN;
    const int t = threadIdx.x;

    float v0 = bf2f(p0[base + t])       + bf2f(p1[base + t])       + bias[t]       + bf2f(resid[base + t]);
    float v1 = bf2f(p0[base + t + 256]) + bf2f(p1[base + t + 256]) + bias[t + 256] + bf2f(resid[base + t + 256]);
    float v2 = bf2f(p0[base + t + 512]) + bf2f(p1[base + t + 512]) + bias[t + 512] + bf2f(resid[base + t + 512]);

    __shared__ float red[4];
    float s = v0 + v1 + v2;
    #pragma unroll
    for (int off = 32; off > 0; off >>= 1) s += __shfl_xor(s, off);
    if ((t & 63) == 0) red[t >> 6] = s;
    __syncthreads();
    float mean = (red[0] + red[1] + red[2] + red[3]) * (1.0f / 768.0f);

    float d0 = v0 - mean, d1 = v1 - mean, d2 = v2 - mean;
    float vs = d0 * d0 + d1 * d1 + d2 * d2;
    #pragma unroll
    for (int off = 32; off > 0; off >>= 1) vs += __shfl_xor(vs, off);
    __syncthreads();
    if ((t & 63) == 0) red[t >> 6] = vs;
    __syncthreads();
    float var = (red[0] + red[1] + red[2] + red[3]) * (1.0f / 768.0f);
    float rstd = rsqrtf(var + 1e-12f);

    out[base + t]       = d0 * rstd * g[t]       + b[t];
    out[base + t + 256] = d1 * rstd * g[t + 256] + b[t + 256];
    out[base + t + 512] = d2 * rstd * g[t + 512] + b[t + 512];
}

// ---------------------------------------------------------------------------
extern "C" void kernel_launch(void* const* d_in, const int* in_sizes, int n_in,
                              void* d_out, int out_size, void* d_ws, size_t ws_size,
                              hipStream_t stream) {
    const float* hs       = (const float*)d_in[0];
    const float* mask     = (const float*)d_in[1];
    const float* past_key = (const float*)d_in[2];
    const float* Wq = (const float*)d_in[4];
    const float* bq = (const float*)d_in[5];
    const float* Wk = (const float*)d_in[6];
    const float* bk = (const float*)d_in[7];
    const float* Wv = (const float*)d_in[8];
    const float* bv = (const float*)d_in[9];
    const float* Wo = (const float*)d_in[10];
    const float* bo = (const float*)d_in[11];
    const float* ln1_g = (const float*)d_in[12];
    const float* ln1_b = (const float*)d_in[13];
    const float* Wi = (const float*)d_in[14];
    const float* bi = (const float*)d_in[15];
    const float* Wf = (const float*)d_in[16];
    const float* bf_ = (const float*)d_in[17];
    const float* ln2_g = (const float*)d_in[18];
    const float* ln2_b = (const float*)d_in[19];
    float* out = (float*)d_out;

    char* w = (char*)d_ws;
    ushort* WqT   = (ushort*)(w + 0);
    ushort* WoT   = (ushort*)(w + 3538944);
    ushort* WiT   = (ushort*)(w + 4718592);
    ushort* WfT   = (ushort*)(w + 9437184);
    float*  bqkv  = (float*)(w + 14155776);
    ushort* hs_bf = (ushort*)(w + 14172160);
    ushort* qkv   = (ushort*)(w + 26755072);
    ushort* kf    = (ushort*)(w + 64503808);
    ushort* vt    = (ushort*)(w + 78315520);
    ushort* ctx_bf = hs_bf;
    ushort* tmp_bf = (ushort*)(w + 64503808);
    ushort* inter  = (ushort*)(w + 14172160);
    ushort* pbuf   = (ushort*)(w + 64503808);
    ushort* aln_bf = (ushort*)(w + 89669632);
    ushort* WkT = WqT + (size_t)HDN * HDN;
    ushort* WvT = WqT + (size_t)2 * HDN * HDN;

    dim3 b256(256);

    prep<<<dim3(13065), b256, 0, stream>>>(
        hs, hs_bf, bq, bk, bv, bqkv,
        Wq, Wk, Wv, Wo, WqT, WkT, WvT, WoT, Wi, WiT, Wf, WfT);

    gemm_t<0, 128><<<dim3(MTOK / 128, QKVN / 128), b256, 0, stream>>>(
        hs_bf, WqT, HDN, HDN, bqkv, nullptr, nullptr, qkv, MTOK, QKVN, HDN);

    kvAll<<<dim3(NBH * 9), b256, 0, stream>>>(qkv, past_key, kf, vt);

    attn4<<<dim3(NBH * 8), b256, 0, stream>>>(qkv, kf, vt, mask, ctx_bf);

    gemm_t<1, 64><<<dim3(MTOK / 128, HDN / 64), b256, 0, stream>>>(
        ctx_bf, WoT, HDN, HDN, bo, hs, nullptr, tmp_bf, MTOK, HDN, HDN);
    layernorm3<<<dim3(MTOK), b256, 0, stream>>>(tmp_bf, ln1_g, ln1_b, nullptr, aln_bf);

    gemm_t<2, 128><<<dim3(MTOK / 128, FFDIM / 128), b256, 0, stream>>>(
        aln_bf, WiT, HDN, HDN, bi, nullptr, nullptr, inter, MTOK, FFDIM, HDN);
    gemm_t<5, 128><<<dim3(MTOK / 128, HDN / 128, 2), b256, 0, stream>>>(
        inter, WfT, FFDIM, FFDIM, nullptr, nullptr, nullptr, pbuf, MTOK, HDN, FFDIM / 2);

    ln_red<<<dim3(MTOK), b256, 0, stream>>>(
        pbuf, pbuf + (size_t)MTOK * HDN, bf_, aln_bf, ln2_g, ln2_b, out);
}

// Round 18
// 243.966 us; speedup vs baseline: 2.2651x; 2.2651x over previous
//
#include <hip/hip_runtime.h>
#include <math.h>

#define HDIM 64
#define NHEAD 12
#define HDN 768
#define QKVN 2304
#define FFDIM 3072
#define LPAST 50
#define SEQ 512
#define NBATCH 16
#define TKV (LPAST + SEQ)     // 562
#define TKVP 576
#define MTOK (NBATCH * SEQ)   // 8192
#define NBH (NBATCH * NHEAD)  // 192

typedef __attribute__((ext_vector_type(8))) short short8;
typedef __attribute__((ext_vector_type(4))) float f32x4;

__device__ __forceinline__ ushort f2bf(float x) {
    union { float f; unsigned u; } c; c.f = x;
    unsigned r = (c.u + 0x7fffu + ((c.u >> 16) & 1u)) >> 16;
    return (ushort)r;
}
__device__ __forceinline__ float bf2f(ushort u) { return __uint_as_float((unsigned)u << 16); }
__device__ __forceinline__ float gelu_fast(float v) {
    float u = 0.7978845608f * v * fmaf(0.044715f * v, v, 1.0f);
    float e = __expf(2.0f * u);
    float th = 1.0f - 2.0f / (e + 1.0f);
    return 0.5f * v * (1.0f + th);
}

#define GLOAD_LDS16(gsrc, ldst)                                                    \
    __builtin_amdgcn_global_load_lds(                                              \
        (const __attribute__((address_space(1))) void*)(gsrc),                     \
        (__attribute__((address_space(3))) void*)(ldst), 16, 0, 0)

// ---------------------------------------------------------------------------
// prep: fused prologue (cast hs, pack qkv bias, all weight transposes)
// ---------------------------------------------------------------------------
__global__ __launch_bounds__(256) void prep(
    const float* __restrict__ hs, ushort* __restrict__ hs_bf,
    const float* __restrict__ bq, const float* __restrict__ bk,
    const float* __restrict__ bv, float* __restrict__ bqkv,
    const float* __restrict__ Wq, const float* __restrict__ Wk,
    const float* __restrict__ Wv, const float* __restrict__ Wo,
    ushort* __restrict__ WqT, ushort* __restrict__ WkT,
    ushort* __restrict__ WvT, ushort* __restrict__ WoT,
    const float* __restrict__ Wi, ushort* __restrict__ WiT,
    const float* __restrict__ Wf, ushort* __restrict__ WfT)
{
    __shared__ float tls[32][33];
    int bid = blockIdx.x;
    const int tid = threadIdx.x;

    if (bid < 6144) {
        int i = bid * 256 + tid;
        float4 v = ((const float4*)hs)[i];
        ushort4 o; o.x = f2bf(v.x); o.y = f2bf(v.y); o.z = f2bf(v.z); o.w = f2bf(v.w);
        ((ushort4*)hs_bf)[i] = o;
        return;
    }
    bid -= 6144;
    if (bid < 9) {
        int i = bid * 256 + tid;
        bqkv[i] = i < HDN ? bq[i] : (i < 2 * HDN ? bk[i - HDN] : bv[i - 2 * HDN]);
        return;
    }
    bid -= 9;

    const float* W; ushort* WT; int K, N, bx, by;
    if (bid < 2304) {
        int z = bid / 576, r = bid % 576;
        W = z == 0 ? Wq : z == 1 ? Wk : z == 2 ? Wv : Wo;
        WT = z == 0 ? WqT : z == 1 ? WkT : z == 2 ? WvT : WoT;
        K = HDN; N = HDN; bx = r % 24; by = r / 24;
    } else if (bid < 4608) {
        int r = bid - 2304; W = Wi; WT = WiT; K = HDN; N = FFDIM; bx = r % 96; by = r / 96;
    } else {
        int r = bid - 4608; W = Wf; WT = WfT; K = FFDIM; N = HDN; bx = r % 24; by = r / 24;
    }
    const int n0 = bx * 32, k0 = by * 32;
    const int tx = tid & 31, ty = tid >> 5;
    #pragma unroll
    for (int i = 0; i < 4; ++i)
        tls[ty + i * 8][tx] = W[(size_t)(k0 + ty + i * 8) * N + n0 + tx];
    __syncthreads();
    #pragma unroll
    for (int i = 0; i < 4; ++i)
        WT[(size_t)(n0 + ty + i * 8) * K + k0 + tx] = f2bf(tls[tx][ty + i * 8]);
}

// ---------------------------------------------------------------------------
// gemm_t: 128xBN-tile bf16 MFMA GEMM (NT), BK=64, double-buffered LDS.
// Operand-swapped MFMA (C fragment: row=lane&15, col=(lane>>4)*4+rr ->
// packed ushort4 stores). st_16x32 XOR swizzle per 32-k half.
// Split-K via blockIdx.z. EPI: 0=+bias ; 1=+bias+resid(f32) ;
// 2=FAST-gelu(+bias) ; 4=+bias+resid(bf16) ; 5=raw partial. bf16 out.
// NOTE: launch_bounds min-waves kept at 2/3 — higher values cap the unified
// VGPR/AGPR budget below the accumulator footprint and spill (R16: 2.2x).
// ---------------------------------------------------------------------------
template<int EPI, int BN>
__global__ __launch_bounds__(256, BN == 64 ? 3 : 2) void gemm_t(
    const ushort* __restrict__ A, const ushort* __restrict__ B,
    int lda, int ldb,
    const float* __restrict__ bias, const float* __restrict__ resid,
    const ushort* __restrict__ resid_bf,
    ushort* __restrict__ Cout, int M, int N, int K)
{
    constexpr int NF = BN / 32;
    constexpr int NBL = BN / 32;
    constexpr int BHS = BN * 4;
    constexpr int BHU = BN * 32;
    constexpr int BUFU = 8192 + BN * 64;
    __shared__ ushort sm[2 * BUFU];

    const int tid = threadIdx.x;
    const int lane = tid & 63;
    const int wv = tid >> 6;
    const int wr = wv >> 1, wc = wv & 1;
    const int bm = blockIdx.x * 128, bn = blockIdx.y * BN;
    const int lr = lane & 15, lg = lane >> 4;
    const int swzu = ((lr * 64 + lg * 16) ^ ((lr & 8) << 2)) >> 1;
    const size_t kzoff = (size_t)blockIdx.z * K;

    int arow[4], akk[4], brow[NBL], bkk[NBL];
    #pragma unroll
    for (int r = 0; r < 4; ++r) {
        int sl = tid + 256 * r;
        int half = sl >> 9, within = sl & 511;
        int o = within * 16;
        int st = o >> 10, q = o & 1023;
        q ^= ((q >> 9) & 1) << 5;
        arow[r] = st * 16 + (q >> 6);
        akk[r] = half * 32 + ((q & 63) >> 1);
    }
    #pragma unroll
    for (int r = 0; r < NBL; ++r) {
        int sl = tid + 256 * r;
        int half = sl / BHS, within = sl % BHS;
        int o = within * 16;
        int st = o >> 10, q = o & 1023;
        q ^= ((q >> 9) & 1) << 5;
        brow[r] = st * 16 + (q >> 6);
        bkk[r] = half * 32 + ((q & 63) >> 1);
    }
    const ushort* Abase = A + (size_t)bm * lda + kzoff;
    const ushort* Bbase = B + (size_t)bn * ldb + kzoff;
    const int nt = K >> 6;

    f32x4 acc[4][NF] = {};

#define STAGE(T, BUF)                                                            \
    do {                                                                         \
        const int k0_ = (T) << 6;                                                \
        char* base_ = (char*)(sm + (BUF) * BUFU);                                \
        _Pragma("unroll")                                                        \
        for (int r_ = 0; r_ < 4; ++r_)                                           \
            GLOAD_LDS16(Abase + (size_t)arow[r_] * lda + k0_ + akk[r_],          \
                        base_ + (tid + 256 * r_) * 16);                          \
        _Pragma("unroll")                                                        \
        for (int r_ = 0; r_ < NBL; ++r_)                                         \
            GLOAD_LDS16(Bbase + (size_t)brow[r_] * ldb + k0_ + bkk[r_],          \
                        base_ + 16384 + (tid + 256 * r_) * 16);                  \
    } while (0)

    STAGE(0, 0);
    asm volatile("s_waitcnt vmcnt(0)" ::: "memory");
    __builtin_amdgcn_sched_barrier(0);
    __builtin_amdgcn_s_barrier();
    __builtin_amdgcn_sched_barrier(0);

    int buf = 0;
    for (int t = 0; t < nt; ++t) {
        if (t + 1 < nt) STAGE(t + 1, buf ^ 1);
        const ushort* ab = sm + buf * BUFU;
        short8 af[4][2], bfv[NF][2];
        #pragma unroll
        for (int i = 0; i < 4; ++i)
            #pragma unroll
            for (int h = 0; h < 2; ++h)
                af[i][h] = *(const short8*)(ab + h * 4096 + (wr * 4 + i) * 512 + swzu);
        #pragma unroll
        for (int j = 0; j < NF; ++j)
            #pragma unroll
            for (int h = 0; h < 2; ++h)
                bfv[j][h] = *(const short8*)(ab + 8192 + h * BHU + (wc * NF + j) * 512 + swzu);
        __builtin_amdgcn_s_setprio(1);
        #pragma unroll
        for (int i = 0; i < 4; ++i)
            #pragma unroll
            for (int j = 0; j < NF; ++j) {
                acc[i][j] = __builtin_amdgcn_mfma_f32_16x16x32_bf16(
                    bfv[j][0], af[i][0], acc[i][j], 0, 0, 0);
                acc[i][j] = __builtin_amdgcn_mfma_f32_16x16x32_bf16(
                    bfv[j][1], af[i][1], acc[i][j], 0, 0, 0);
            }
        __builtin_amdgcn_s_setprio(0);
        asm volatile("s_waitcnt vmcnt(0)" ::: "memory");
        __builtin_amdgcn_sched_barrier(0);
        __builtin_amdgcn_s_barrier();
        __builtin_amdgcn_sched_barrier(0);
        buf ^= 1;
    }
#undef STAGE

    ushort* Cz = Cout + (size_t)blockIdx.z * M * N;
    #pragma unroll
    for (int i = 0; i < 4; ++i) {
        const int row = bm + wr * 64 + i * 16 + lr;
        #pragma unroll
        for (int j = 0; j < NF; ++j) {
            const int col = bn + wc * (BN / 2) + j * 16 + lg * 4;
            const size_t idx = (size_t)row * N + col;
            float v0 = acc[i][j][0], v1 = acc[i][j][1],
                  v2 = acc[i][j][2], v3 = acc[i][j][3];
            if (EPI != 5) {
                float4 b4 = *(const float4*)&bias[col];
                v0 += b4.x; v1 += b4.y; v2 += b4.z; v3 += b4.w;
            }
            if (EPI == 1) {
                float4 r4 = *(const float4*)&resid[idx];
                v0 += r4.x; v1 += r4.y; v2 += r4.z; v3 += r4.w;
            }
            if (EPI == 4) {
                ushort4 rb = *(const ushort4*)&resid_bf[idx];
                v0 += bf2f(rb.x); v1 += bf2f(rb.y);
                v2 += bf2f(rb.z); v3 += bf2f(rb.w);
            }
            if (EPI == 2) {
                v0 = gelu_fast(v0); v1 = gelu_fast(v1);
                v2 = gelu_fast(v2); v3 = gelu_fast(v3);
            }
            ushort4 o;
            o.x = f2bf(v0); o.y = f2bf(v1); o.z = f2bf(v2); o.w = f2bf(v3);
            *(ushort4*)&Cz[idx] = o;
        }
    }
}

// ---------------------------------------------------------------------------
// kvAll: fused K cache + transposed V cache (bug-faithful past_key prefix).
// ---------------------------------------------------------------------------
__global__ __launch_bounds__(256) void kvAll(
    const ushort* __restrict__ qkv, const float* __restrict__ past_key,
    ushort* __restrict__ kf, ushort* __restrict__ vt)
{
    __shared__ ushort td[64][72];
    const int bh = blockIdx.x / 9;
    const int t0 = (blockIdx.x % 9) * 64;
    const int b = bh / NHEAD, h = bh % NHEAD;
    const int trow = threadIdx.x >> 2, seg = threadIdx.x & 3;
    const int t = t0 + trow;

    ushort kv16[16], vv16[16];
    if (t < LPAST) {
        const float* pk = past_key + ((size_t)bh * LPAST + t) * HDIM + seg * 16;
        #pragma unroll
        for (int i = 0; i < 4; ++i) {
            float4 f = ((const float4*)pk)[i];
            kv16[i * 4 + 0] = f2bf(f.x); kv16[i * 4 + 1] = f2bf(f.y);
            kv16[i * 4 + 2] = f2bf(f.z); kv16[i * 4 + 3] = f2bf(f.w);
        }
        #pragma unroll
        for (int i = 0; i < 16; ++i) vv16[i] = kv16[i];
    } else if (t < TKV) {
        const ushort* kp = qkv + ((size_t)(b * SEQ + (t - LPAST))) * QKVN
                               + HDN + h * HDIM + seg * 16;
        *(uint4*)&kv16[0] = ((const uint4*)kp)[0];
        *(uint4*)&kv16[8] = ((const uint4*)kp)[1];
        const ushort* vp = kp + HDN;
        *(uint4*)&vv16[0] = ((const uint4*)vp)[0];
        *(uint4*)&vv16[8] = ((const uint4*)vp)[1];
    } else {
        #pragma unroll
        for (int i = 0; i < 16; ++i) { kv16[i] = 0; vv16[i] = 0; }
    }

    if (t < TKV) {
        ushort* kd = kf + (((size_t)bh * TKV + t) << 6) + seg * 16;
        *(uint4*)kd = *(uint4*)&kv16[0];
        *(uint4*)(kd + 8) = *(uint4*)&kv16[8];
    }

    #pragma unroll
    for (int i = 0; i < 16; ++i) td[trow][seg * 16 + i] = vv16[i];
    __syncthreads();

    const int d = threadIdx.x >> 2;
    ushort o[16];
    #pragma unroll
    for (int i = 0; i < 16; ++i) o[i] = td[seg * 16 + i][d];
    ushort* dst = vt + ((size_t)bh * HDIM + d) * TKVP + t0 + seg * 16;
    *(uint4*)dst = *(uint4*)&o[0];
    *(uint4*)(dst + 8) = *(uint4*)&o[8];
}

// ---------------------------------------------------------------------------
// attn4: MFMA flash attention, fixed-max softmax (scores bounded; see R9).
// XCD-grouped blockIdx remap. (Best-measured R14 version, unchanged.)
// ---------------------------------------------------------------------------
__global__ __launch_bounds__(256) void attn4(
    const ushort* __restrict__ qkv, const ushort* __restrict__ kf,
    const ushort* __restrict__ vt, const float* __restrict__ mask,
    ushort* __restrict__ ctx)
{
    __shared__ ushort Ks[64 * 64];
    __shared__ ushort Vs[64 * 64];
    __shared__ ushort Ps[4][16 * 64];

    const int wv = threadIdx.x >> 6, lane = threadIdx.x & 63;
    const int lr = lane & 15, lg = lane >> 4;
    const int bid = blockIdx.x;
    const int xcd = bid & 7, gi = bid >> 3;
    const int bh = xcd * (NBH / 8) + (gi >> 3);
    const int s0 = (gi & 7) * 64;
    const int b = bh / NHEAD, h = bh % NHEAD;

    short8 af[2];
    {
        const ushort* qp = qkv + ((size_t)(b * SEQ + s0 + wv * 16 + lr)) * QKVN
                               + h * HDIM + lg * 8;
        af[0] = *(const short8*)qp;
        af[1] = *(const short8*)(qp + 32);
    }

    const ushort* kbase = kf + (size_t)bh * TKV * HDIM;
    const ushort* vbase = vt + (size_t)bh * HDIM * TKVP;

    float l[4] = {};
    f32x4 ctxa[4] = {};

    for (int kt = 0; kt < 9; ++kt) {
        const int t0 = kt * 64;
        #pragma unroll
        for (int r = 0; r < 2; ++r) {
            int sl = (int)threadIdx.x + 256 * r;
            int row = sl >> 3, p = sl & 7;
            int j = p ^ (row & 7);
            int trow = t0 + row; if (trow > TKV - 1) trow = TKV - 1;
            GLOAD_LDS16(kbase + ((size_t)trow << 6) + j * 8, (char*)Ks + sl * 16);
        }
        #pragma unroll
        for (int r = 0; r < 2; ++r) {
            int sl = (int)threadIdx.x + 256 * r;
            int row = sl >> 3, p = sl & 7;
            int j = p ^ (row & 7);
            GLOAD_LDS16(vbase + (size_t)row * TKVP + t0 + j * 8, (char*)Vs + sl * 16);
        }
        __syncthreads();

        f32x4 sa[4] = {};
        #pragma unroll
        for (int kb = 0; kb < 4; ++kb) {
            const int key = kb * 16 + lr;
            #pragma unroll
            for (int c = 0; c < 2; ++c) {
                const int phys = (c * 4 + lg) ^ (key & 7);
                short8 kfrag = *(const short8*)&Ks[key * 64 + phys * 8];
                sa[kb] = __builtin_amdgcn_mfma_f32_16x16x32_bf16(
                    af[c], kfrag, sa[kb], 0, 0, 0);
            }
        }

        #pragma unroll
        for (int kb = 0; kb < 4; ++kb) {
            const int t = t0 + kb * 16 + lr;
            float addv;
            if (t >= TKV) addv = -1e30f;
            else addv = ((t < LPAST) ? 1.0f : mask[(size_t)b * SEQ + (t - LPAST)]) - 4.0f;
            const int key = kb * 16 + lr;
            #pragma unroll
            for (int r = 0; r < 4; ++r) {
                float p = __expf(fmaf(sa[kb][r], 0.125f, addv));
                l[r] += p;
                const int q_ = lg * 4 + r;
                const int phys = (key >> 3) ^ (q_ & 7);
                Ps[wv][q_ * 64 + phys * 8 + (key & 7)] = f2bf(p);
            }
        }

        short8 pa[2];
        #pragma unroll
        for (int c = 0; c < 2; ++c) {
            const int phys = (c * 4 + lg) ^ (lr & 7);
            pa[c] = *(const short8*)&Ps[wv][lr * 64 + phys * 8];
        }
        #pragma unroll
        for (int dg = 0; dg < 4; ++dg) {
            const int d = dg * 16 + lr;
            #pragma unroll
            for (int c = 0; c < 2; ++c) {
                const int phys = (c * 4 + lg) ^ (d & 7);
                short8 vfrag = *(const short8*)&Vs[d * 64 + phys * 8];
                ctxa[dg] = __builtin_amdgcn_mfma_f32_16x16x32_bf16(
                    pa[c], vfrag, ctxa[dg], 0, 0, 0);
            }
        }
        __syncthreads();
    }

    #pragma unroll
    for (int r = 0; r < 4; ++r) {
        float s = l[r];
        s += __shfl_xor(s, 1); s += __shfl_xor(s, 2);
        s += __shfl_xor(s, 4); s += __shfl_xor(s, 8);
        l[r] = 1.0f / s;
    }
    #pragma unroll
    for (int r = 0; r < 4; ++r) {
        const int q_ = s0 + wv * 16 + lg * 4 + r;
        const size_t base = ((size_t)(b * SEQ + q_)) * HDN + h * HDIM;
        #pragma unroll
        for (int dg = 0; dg < 4; ++dg)
            ctx[base + dg * 16 + lr] = f2bf(ctxa[dg][r] * l[r]);
    }
}

// ---------------------------------------------------------------------------
// LayerNorm(768) over bf16 input; f32 out and/or bf16 out (either null).
// ---------------------------------------------------------------------------
__global__ __launch_bounds__(256) void layernorm3(
    const ushort* __restrict__ x, const float* __restrict__ g,
    const float* __restrict__ b, float* __restrict__ out,
    ushort* __restrict__ out_bf)
{
    const size_t row = blockIdx.x;
    const ushort* xr = &x[row * HDN];
    const int t = threadIdx.x;

    float v0 = bf2f(xr[t]), v1 = bf2f(xr[t + 256]), v2 = bf2f(xr[t + 512]);

    __shared__ float red[4];
    float s = v0 + v1 + v2;
    #pragma unroll
    for (int off = 32; off > 0; off >>= 1) s += __shfl_xor(s, off);
    if ((t & 63) == 0) red[t >> 6] = s;
    __syncthreads();
    float mean = (red[0] + red[1] + red[2] + red[3]) * (1.0f / 768.0f);

    float d0 = v0 - mean, d1 = v1 - mean, d2 = v2 - mean;
    float vs = d0 * d0 + d1 * d1 + d2 * d2;
    #pragma unroll
    for (int off = 32; off > 0; off >>= 1) vs += __shfl_xor(vs, off);
    __syncthreads();
    if ((t & 63) == 0) red[t >> 6] = vs;
    __syncthreads();
    float var = (red[0] + red[1] + red[2] + red[3]) * (1.0f / 768.0f);
    float rstd = rsqrtf(var + 1e-12f);

    float o0 = d0 * rstd * g[t] + b[t];
    float o1 = d1 * rstd * g[t + 256] + b[t + 256];
    float o2 = d2 * rstd * g[t + 512] + b[t + 512];
    if (out) {
        out[row * HDN + t] = o0;
        out[row * HDN + t + 256] = o1;
        out[row * HDN + t + 512] = o2;
    }
    if (out_bf) {
        out_bf[row * HDN + t] = f2bf(o0);
        out_bf[row * HDN + t + 256] = f2bf(o1);
        out_bf[row * HDN + t + 512] = f2bf(o2);
    }
}

// ---------------------------------------------------------------------------
// ln_red: fused split-K reduce (p0+p1+bias+resid) + LayerNorm -> f32 out.
// ---------------------------------------------------------------------------
__global__ __launch_bounds__(256) void ln_red(
    const ushort* __restrict__ p0, const ushort* __restrict__ p1,
    const float* __restrict__ bias, const ushort* __restrict__ resid,
    const float* __restrict__ g, const float* __restrict__ b,
    float* __restrict__ out)
{
    const size_t row = blockIdx.x;
    const size_t base = row * HDN;
    const int t = threadIdx.x;

    float v0 = bf2f(p0[base + t])       + bf2f(p1[base + t])       + bias[t]       + bf2f(resid[base + t]);
    float v1 = bf2f(p0[base + t + 256]) + bf2f(p1[base + t + 256]) + bias[t + 256] + bf2f(resid[base + t + 256]);
    float v2 = bf2f(p0[base + t + 512]) + bf2f(p1[base + t + 512]) + bias[t + 512] + bf2f(resid[base + t + 512]);

    __shared__ float red[4];
    float s = v0 + v1 + v2;
    #pragma unroll
    for (int off = 32; off > 0; off >>= 1) s += __shfl_xor(s, off);
    if ((t & 63) == 0) red[t >> 6] = s;
    __syncthreads();
    float mean = (red[0] + red[1] + red[2] + red[3]) * (1.0f / 768.0f);

    float d0 = v0 - mean, d1 = v1 - mean, d2 = v2 - mean;
    float vs = d0 * d0 + d1 * d1 + d2 * d2;
    #pragma unroll
    for (int off = 32; off > 0; off >>= 1) vs += __shfl_xor(vs, off);
    __syncthreads();
    if ((t & 63) == 0) red[t >> 6] = vs;
    __syncthreads();
    float var = (red[0] + red[1] + red[2] + red[3]) * (1.0f / 768.0f);
    float rstd = rsqrtf(var + 1e-12f);

    out[base + t]       = d0 * rstd * g[t]       + b[t];
    out[base + t + 256] = d1 * rstd * g[t + 256] + b[t + 256];
    out[base + t + 512] = d2 * rstd * g[t + 512] + b[t + 512];
}

// ---------------------------------------------------------------------------
extern "C" void kernel_launch(void* const* d_in, const int* in_sizes, int n_in,
                              void* d_out, int out_size, void* d_ws, size_t ws_size,
                              hipStream_t stream) {
    const float* hs       = (const float*)d_in[0];
    const float* mask     = (const float*)d_in[1];
    const float* past_key = (const float*)d_in[2];
    const float* Wq = (const float*)d_in[4];
    const float* bq = (const float*)d_in[5];
    const float* Wk = (const float*)d_in[6];
    const float* bk = (const float*)d_in[7];
    const float* Wv = (const float*)d_in[8];
    const float* bv = (const float*)d_in[9];
    const float* Wo = (const float*)d_in[10];
    const float* bo = (const float*)d_in[11];
    const float* ln1_g = (const float*)d_in[12];
    const float* ln1_b = (const float*)d_in[13];
    const float* Wi = (const float*)d_in[14];
    const float* bi = (const float*)d_in[15];
    const float* Wf = (const float*)d_in[16];
    const float* bf_ = (const float*)d_in[17];
    const float* ln2_g = (const float*)d_in[18];
    const float* ln2_b = (const float*)d_in[19];
    float* out = (float*)d_out;

    char* w = (char*)d_ws;
    ushort* WqT   = (ushort*)(w + 0);
    ushort* WoT   = (ushort*)(w + 3538944);
    ushort* WiT   = (ushort*)(w + 4718592);
    ushort* WfT   = (ushort*)(w + 9437184);
    float*  bqkv  = (float*)(w + 14155776);
    ushort* hs_bf = (ushort*)(w + 14172160);
    ushort* qkv   = (ushort*)(w + 26755072);
    ushort* kf    = (ushort*)(w + 64503808);
    ushort* vt    = (ushort*)(w + 78315520);
    ushort* ctx_bf = hs_bf;
    ushort* tmp_bf = (ushort*)(w + 64503808);
    ushort* inter  = (ushort*)(w + 14172160);
    ushort* pbuf   = (ushort*)(w + 64503808);
    ushort* aln_bf = (ushort*)(w + 89669632);
    ushort* WkT = WqT + (size_t)HDN * HDN;
    ushort* WvT = WqT + (size_t)2 * HDN * HDN;

    dim3 b256(256);

    prep<<<dim3(13065), b256, 0, stream>>>(
        hs, hs_bf, bq, bk, bv, bqkv,
        Wq, Wk, Wv, Wo, WqT, WkT, WvT, WoT, Wi, WiT, Wf, WfT);

    gemm_t<0, 128><<<dim3(MTOK / 128, QKVN / 128), b256, 0, stream>>>(
        hs_bf, WqT, HDN, HDN, bqkv, nullptr, nullptr, qkv, MTOK, QKVN, HDN);

    kvAll<<<dim3(NBH * 9), b256, 0, stream>>>(qkv, past_key, kf, vt);

    attn4<<<dim3(NBH * 8), b256, 0, stream>>>(qkv, kf, vt, mask, ctx_bf);

    gemm_t<1, 64><<<dim3(MTOK / 128, HDN / 64), b256, 0, stream>>>(
        ctx_bf, WoT, HDN, HDN, bo, hs, nullptr, tmp_bf, MTOK, HDN, HDN);
    layernorm3<<<dim3(MTOK), b256, 0, stream>>>(tmp_bf, ln1_g, ln1_b, nullptr, aln_bf);

    gemm_t<2, 128><<<dim3(MTOK / 128, FFDIM / 128), b256, 0, stream>>>(
        aln_bf, WiT, HDN, HDN, bi, nullptr, nullptr, inter, MTOK, FFDIM, HDN);
    gemm_t<5, 128><<<dim3(MTOK / 128, HDN / 128, 2), b256, 0, stream>>>(
        inter, WfT, FFDIM, FFDIM, nullptr, nullptr, nullptr, pbuf, MTOK, HDN, FFDIM / 2);

    ln_red<<<dim3(MTOK), b256, 0, stream>>>(
        pbuf, pbuf + (size_t)MTOK * HDN, bf_, aln_bf, ln2_g, ln2_b, out);
}